// Round 2
// baseline (82.021 us; speedup 1.0000x reference)
//
#include <hip/hip_runtime.h>
#include <math.h>

// Problem constants (fixed by reference setup_inputs)
#define BB 128
#define LL 512
#define DD 256
#define TT 64
#define GG 8   // LL / TT

typedef float f32x4 __attribute__((ext_vector_type(4)));

__device__ __forceinline__ float sigm(float x) {
    return 1.0f / (1.0f + __expf(-x));
}

// Kernel 1: group-pool both modalities (float4 lanes), emit c_att + hw,
// wave-reduce hw over D for hwRowMean.
// grid = BB*TT/4 blocks, 256 threads; each 64-lane wave owns one (b,t) row.
__global__ void k_pool(const f32x4* __restrict__ aco, const f32x4* __restrict__ vis,
                       const float* __restrict__ conv_w, const float* __restrict__ conv_b,
                       f32x4* __restrict__ c_att, f32x4* __restrict__ hw_buf,
                       float* __restrict__ hwRowMean)
{
    const int tid = threadIdx.x;
    const int q   = tid & 63;        // float4 index within D-row (64 per row)
    const int r   = tid >> 6;        // which of the 4 pooled rows this block owns
    const int bt  = blockIdx.x * 4 + r;
    const int b   = bt >> 6;
    const int t   = bt & 63;

    size_t base = ((size_t)(b * LL + t * GG)) * (DD / 4) + q;
    f32x4 sa = 0.f, sv = 0.f;
#pragma unroll
    for (int g = 0; g < GG; ++g) {
        sa += aco[base + (size_t)g * (DD / 4)];
        sv += vis[base + (size_t)g * (DD / 4)];
    }
    sa *= 0.125f;
    sv *= 0.125f;

    const float cw0 = conv_w[0], cw1 = conv_w[1], cb = conv_b[0];
    f32x4 z  = cw0 * sa + cw1 * sv + cb;
    f32x4 ca;
    ca.x = sigm(z.x); ca.y = sigm(z.y); ca.z = sigm(z.z); ca.w = sigm(z.w);
    f32x4 hw = 0.5f * (sa + sv);

    c_att[(size_t)bt * (DD / 4) + q]  = ca;
    hw_buf[(size_t)bt * (DD / 4) + q] = hw;

    // wave-level reduce of hw over the D dimension (64 lanes == one wave)
    float hsum = hw.x + hw.y + hw.z + hw.w;
#pragma unroll
    for (int off = 32; off > 0; off >>= 1)
        hsum += __shfl_xor(hsum, off, 64);
    if (q == 0) hwRowMean[bt] = hsum * (1.0f / DD);
}

// Kernel 2 (fused gates): h_att = sigmoid(hwRowMean @ Wh^T + bh),
// w_att = sigmoid(colmean(hw) @ Ww^T + bw).  grid = BB, block = DD.
__global__ void k_gates(const float* __restrict__ hw_buf, const float* __restrict__ hwRowMean,
                        const float* __restrict__ Wh, const float* __restrict__ bh,
                        const float* __restrict__ Ww, const float* __restrict__ bw,
                        float* __restrict__ h_att, float* __restrict__ w_att)
{
    const int b = blockIdx.x;
    const int d = threadIdx.x;  // 0..255

    __shared__ float row[TT];
    __shared__ float cm[DD];

    if (d < TT) row[d] = hwRowMean[b * TT + d];

    // column mean over T (coalesced: consecutive d -> consecutive addresses)
    float s = 0.f;
    const float* hb = hw_buf + (size_t)b * TT * DD + d;
#pragma unroll
    for (int t = 0; t < TT; ++t) s += hb[(size_t)t * DD];
    cm[d] = s * (1.0f / TT);
    __syncthreads();

    if (d < TT) {
        float acc = bh[d];
#pragma unroll
        for (int j = 0; j < TT; ++j) acc += row[j] * Wh[d * TT + j];
        h_att[b * TT + d] = sigm(acc);
    }

    float acc = bw[d];
    const float* wr = Ww + (size_t)d * DD;
#pragma unroll 4
    for (int k = 0; k < DD; k += 4) {
        f32x4 w4 = *reinterpret_cast<const f32x4*>(wr + k);
        acc += cm[k] * w4.x + cm[k + 1] * w4.y + cm[k + 2] * w4.z + cm[k + 3] * w4.w;
    }
    w_att[b * DD + d] = sigm(acc);
}

// Kernel 3: apply scale to both streams. Grid-stride, one float4 per iter.
// Nontemporal output stores: keep the 128 MiB of inputs resident in L3.
__global__ void k_apply(const f32x4* __restrict__ aco, const f32x4* __restrict__ vis,
                        const int* __restrict__ isbag,
                        const f32x4* __restrict__ c_att, const float* __restrict__ h_att,
                        const f32x4* __restrict__ w_att,
                        f32x4* __restrict__ out)
{
    const size_t N4 = (size_t)BB * LL * DD / 4;  // 4M float4
    const size_t stride = (size_t)gridDim.x * blockDim.x;
    for (size_t i = (size_t)blockIdx.x * blockDim.x + threadIdx.x; i < N4; i += stride) {
        const int row = (int)(i >> 6);   // 64 float4 per D-row
        const int dq  = (int)(i & 63);
        const int b   = row >> 9;        // / LL
        const int l   = row & 511;
        const int t   = l >> 3;          // / GG

        const float h  = h_att[b * TT + t];                       // wave-uniform
        const f32x4 w4 = w_att[b * (DD / 4) + dq];
        const f32x4 c4 = c_att[((size_t)(b * TT + t)) * (DD / 4) + dq];
        const bool  m  = (isbag[row] == 1);                       // wave-uniform

        f32x4 a4 = aco[i];
        f32x4 v4 = vis[i];
        f32x4 s4 = (h + w4 + c4) * (1.0f / 3.0f);

        f32x4 oa = m ? (f32x4)(a4 * s4) : a4;
        f32x4 ov = m ? (f32x4)(v4 * s4) : v4;

        __builtin_nontemporal_store(oa, &out[i]);
        __builtin_nontemporal_store(ov, &out[N4 + i]);
    }
}

extern "C" void kernel_launch(void* const* d_in, const int* in_sizes, int n_in,
                              void* d_out, int out_size, void* d_ws, size_t ws_size,
                              hipStream_t stream) {
    const float* aco = (const float*)d_in[0];
    const float* vis = (const float*)d_in[1];
    const int*   isb = (const int*)d_in[2];
    const float* Wh  = (const float*)d_in[3];
    const float* bh  = (const float*)d_in[4];
    const float* Ww  = (const float*)d_in[5];
    const float* bw  = (const float*)d_in[6];
    const float* cw  = (const float*)d_in[7];
    const float* cb  = (const float*)d_in[8];
    float* out = (float*)d_out;

    float* ws = (float*)d_ws;
    float* c_att     = ws;                              // BB*TT*DD = 2M floats
    float* hw_buf    = c_att  + (size_t)BB * TT * DD;   // BB*TT*DD
    float* hwRowMean = hw_buf + (size_t)BB * TT * DD;   // BB*TT
    float* h_att     = hwRowMean + BB * TT;             // BB*TT
    float* w_att     = h_att + BB * TT;                 // BB*DD

    k_pool<<<BB * TT / 4, 256, 0, stream>>>(
        (const f32x4*)aco, (const f32x4*)vis, cw, cb,
        (f32x4*)c_att, (f32x4*)hw_buf, hwRowMean);

    k_gates<<<BB, DD, 0, stream>>>(hw_buf, hwRowMean, Wh, bh, Ww, bw, h_att, w_att);

    k_apply<<<2048, 256, 0, stream>>>(
        (const f32x4*)aco, (const f32x4*)vis, isb,
        (const f32x4*)c_att, h_att, (const f32x4*)w_att,
        (f32x4*)out);
}